// Round 8
// baseline (138.121 us; speedup 1.0000x reference)
//
#include <hip/hip_runtime.h>

#define E_DIM 256
#define S_DIM 2048
#define B_DIM 8

typedef unsigned short u16;
typedef __bf16 bf16x8 __attribute__((ext_vector_type(8)));
typedef float f32x4 __attribute__((ext_vector_type(4)));
typedef u16 u16x8 __attribute__((ext_vector_type(8)));
typedef u16 u16x4 __attribute__((ext_vector_type(4)));

__device__ inline u16 f2bf(float f) {
  unsigned u = __builtin_bit_cast(unsigned, f);
  return (u16)((u + 0x7FFF + ((u >> 16) & 1)) >> 16);  // RTNE, finite inputs
}
__device__ inline float bf2f(u16 v) {
  unsigned u = ((unsigned)v) << 16;
  return __builtin_bit_cast(float, u);
}

// ---------------------------------------------------------------------------
// K_A: x fp32 [b][e][s] -> xT bf16 [b][s][e] (64x64 LDS transpose, proven R2)
//      + weight fp32->bf16 convert folded in (128 elems/block on threads 0..31)
// ---------------------------------------------------------------------------
__global__ __launch_bounds__(256) void transpose_convert(
    const float* __restrict__ x, u16* __restrict__ xT,
    const float* __restrict__ Wq, const float* __restrict__ Wo,
    u16* __restrict__ Wqb, u16* __restrict__ Wob) {
  __shared__ float t[64 * 68];
  const int tid = threadIdx.x;
  const int s0 = blockIdx.x * 64, e0 = blockIdx.y * 64, b = blockIdx.z;

  // folded weight conversion: 1024 blocks x 128 elems = 131072
  if (tid < 32) {
    int bid = (b * 4 + blockIdx.y) * 32 + blockIdx.x;
    int idx = (bid * 32 + tid) * 4;
    const float* src;
    u16* dst;
    if (idx < 65536) { src = Wq + idx; dst = Wqb + idx; }
    else { src = Wo + (idx - 65536); dst = Wob + (idx - 65536); }
    float4 v = *(const float4*)src;
    *(ushort4*)dst = make_ushort4(f2bf(v.x), f2bf(v.y), f2bf(v.z), f2bf(v.w));
  }

  const int sc = (tid & 15) * 4, ei = tid >> 4;
#pragma unroll
  for (int p = 0; p < 4; ++p) {
    int e = e0 + p * 16 + ei;
    float4 v = *(const float4*)&x[((size_t)b * E_DIM + e) * S_DIM + s0 + sc];
    int ee = p * 16 + ei;
    t[(sc + 0) * 68 + ee] = v.x;
    t[(sc + 1) * 68 + ee] = v.y;
    t[(sc + 2) * 68 + ee] = v.z;
    t[(sc + 3) * 68 + ee] = v.w;
  }
  __syncthreads();
#pragma unroll
  for (int c = tid; c < 512; c += 256) {
    int r = c >> 3, h = c & 7;
    const float* p = &t[r * 68 + h * 8];
    u16x8 o;
#pragma unroll
    for (int u = 0; u < 8; ++u) o[u] = f2bf(p[u]);
    *(u16x8*)&xT[((size_t)b * S_DIM + s0 + r) * E_DIM + e0 + h * 8] = o;
  }
}

// ---------------------------------------------------------------------------
// K_B: Y = xT . [Wq;Wo]^T  (M=2048/b, N=512, K=256). 128x128 tile, BK=32,
// 4 waves 2x2, 4x4 16x16x32 frags (R2's proven structure).
// n-half 0 (blockIdx.y<2): Y1[b][s][f] = q = acc + bq  (bf16, scalar stores)
// n-half 1: Y2[b][f][s] = Wo.x (bf16, ushort4 along s)
// ---------------------------------------------------------------------------
__global__ __launch_bounds__(256) void gemm_y(
    const u16* __restrict__ xT, const u16* __restrict__ Wqb,
    const u16* __restrict__ Wob, const float* __restrict__ bq,
    u16* __restrict__ Y1, u16* __restrict__ Y2) {
  __shared__ u16 As[128 * 40];
  __shared__ u16 Bs[128 * 40];
  const int tid = threadIdx.x;
  const int m0 = blockIdx.x * 128, n0 = blockIdx.y * 128, b = blockIdx.z;
  const int wave = tid >> 6, lane = tid & 63;
  const int wm = wave & 1, wn = wave >> 1;
  const int lm = lane & 15, lk = lane >> 4;
  const bool qhalf = (n0 < 256);
  const u16* __restrict__ Ab = xT + (size_t)b * S_DIM * E_DIM;
  const u16* __restrict__ Bw = qhalf ? (Wqb + (size_t)n0 * E_DIM)
                                     : (Wob + (size_t)(n0 - 256) * E_DIM);

  const f32x4 zero = {0.f, 0.f, 0.f, 0.f};
  f32x4 acc[4][4];
#pragma unroll
  for (int i = 0; i < 4; ++i)
#pragma unroll
    for (int j = 0; j < 4; ++j) acc[i][j] = zero;

  for (int k0 = 0; k0 < E_DIM; k0 += 32) {
    __syncthreads();
#pragma unroll
    for (int c = tid; c < 512; c += 256) {
      int r = c >> 2, off = c & 3;
      *(float4*)&As[r * 40 + off * 8] =
          *(const float4*)&Ab[(size_t)(m0 + r) * E_DIM + k0 + off * 8];
    }
#pragma unroll
    for (int c = tid; c < 512; c += 256) {
      int r = c >> 2, off = c & 3;
      *(float4*)&Bs[r * 40 + off * 8] =
          *(const float4*)&Bw[(size_t)r * E_DIM + k0 + off * 8];
    }
    __syncthreads();
    bf16x8 af[4], bfr[4];
#pragma unroll
    for (int i = 0; i < 4; ++i)
      af[i] = *(const bf16x8*)&As[(wm * 64 + i * 16 + lm) * 40 + lk * 8];
#pragma unroll
    for (int j = 0; j < 4; ++j)
      bfr[j] = *(const bf16x8*)&Bs[(wn * 64 + j * 16 + lm) * 40 + lk * 8];
#pragma unroll
    for (int i = 0; i < 4; ++i)
#pragma unroll
      for (int j = 0; j < 4; ++j)
        acc[i][j] = __builtin_amdgcn_mfma_f32_16x16x32_bf16(af[i], bfr[j], acc[i][j], 0, 0, 0);
  }

  if (qhalf) {
    // Y1[b][s][f] bf16 = acc + bq[f]
#pragma unroll
    for (int j = 0; j < 4; ++j) {
      int f = n0 + wn * 64 + j * 16 + lm;
      float bv = bq[f];
#pragma unroll
      for (int i = 0; i < 4; ++i) {
        int m = m0 + wm * 64 + i * 16 + lk * 4;
        size_t base = ((size_t)b * S_DIM + m) * E_DIM + f;
#pragma unroll
        for (int r = 0; r < 4; ++r)
          Y1[base + (size_t)r * E_DIM] = f2bf(acc[i][j][r] + bv);
      }
    }
  } else {
    // Y2[b][f][s] bf16 (no bias)
#pragma unroll
    for (int j = 0; j < 4; ++j) {
      int f = n0 - 256 + wn * 64 + j * 16 + lm;
#pragma unroll
      for (int i = 0; i < 4; ++i) {
        int s = m0 + wm * 64 + i * 16 + lk * 4;
        ushort4 v = make_ushort4(f2bf(acc[i][j][0]), f2bf(acc[i][j][1]),
                                 f2bf(acc[i][j][2]), f2bf(acc[i][j][3]));
        *(ushort4*)&Y2[((size_t)b * E_DIM + f) * S_DIM + s] = v;
      }
    }
  }
}

// ---------------------------------------------------------------------------
// K_C: band kernel. Block = (b, 32-s tile), 512 thr, one barrier.
//  E: energy[s][l] = Y1[s].Y1[s+l-4]/24 (OOB row -> bq), in-wave reduce,
//     softmax -> ldsw[32][9]
//  B: out[b][f][s] = (sum_l w[s][l]*Y2[f][s+l-4] + bo[f]) / 9   (OOB -> 0)
// ---------------------------------------------------------------------------
#define TS 32

__global__ __launch_bounds__(512) void band_blend(
    const u16* __restrict__ Y1, const u16* __restrict__ Y2,
    const float* __restrict__ bq, const float* __restrict__ bo,
    float* __restrict__ out) {
  __shared__ float ldsw[TS * 9];
  const int tid = threadIdx.x;
  const int s0 = blockIdx.x * TS;
  const int b = blockIdx.y;
  const int wave = tid >> 6, lane = tid & 63;

  // ---- Phase E: wave owns s-rows 4w..4w+3; lane halves take si pairs ----
  {
    const int half = lane >> 5;
    const int fl = lane & 31;
    const int sbase = half * 2;
    const u16* __restrict__ y1b = Y1 + (size_t)b * S_DIM * E_DIM;
    float accE[2][9];
#pragma unroll
    for (int si = 0; si < 2; ++si)
#pragma unroll
      for (int l = 0; l < 9; ++l) accE[si][l] = 0.f;
#pragma unroll
    for (int fc = 0; fc < 2; ++fc) {
      int fbase = fl * 8 + fc * 4;
      float4 rr[10];
#pragma unroll
      for (int i = 0; i < 10; ++i) {
        int t = s0 + 4 * wave + sbase - 4 + i;  // wave-uniform branch
        if (t >= 0 && t < S_DIM) {
          u16x4 v = *(const u16x4*)&y1b[(size_t)t * E_DIM + fbase];
          rr[i] = make_float4(bf2f(v[0]), bf2f(v[1]), bf2f(v[2]), bf2f(v[3]));
        } else {
          rr[i] = *(const float4*)&bq[fbase];
        }
      }
#pragma unroll
      for (int si = 0; si < 2; ++si) {
        float4 c = rr[si + 4];
#pragma unroll
        for (int l = 0; l < 9; ++l) {
          float4 r = rr[si + l];
          accE[si][l] += c.x * r.x + c.y * r.y + c.z * r.z + c.w * r.w;
        }
      }
    }
#pragma unroll
    for (int off = 1; off < 32; off <<= 1)
#pragma unroll
      for (int si = 0; si < 2; ++si)
#pragma unroll
        for (int l = 0; l < 9; ++l) accE[si][l] += __shfl_xor(accE[si][l], off, 64);
    if (fl == 0) {
#pragma unroll
      for (int si = 0; si < 2; ++si) {
        int s = 4 * wave + sbase + si;
        float e[9];
#pragma unroll
        for (int l = 0; l < 9; ++l) e[l] = accE[si][l] * (1.0f / 24.0f);
        float m = e[0];
#pragma unroll
        for (int l = 1; l < 9; ++l) m = fmaxf(m, e[l]);
        float sum = 0.f;
#pragma unroll
        for (int l = 0; l < 9; ++l) { e[l] = __expf(e[l] - m); sum += e[l]; }
        float inv = 1.0f / sum;
#pragma unroll
        for (int l = 0; l < 9; ++l) ldsw[s * 9 + l] = e[l] * inv;
      }
    }
  }
  __syncthreads();

  // ---- Phase B: blend Y2 rows with banded weights ----
  {
    const int s = tid & 31;       // lane-contiguous s for coalescing
    const int fi = tid >> 5;      // 0..15
    float w9[9];
#pragma unroll
    for (int l = 0; l < 9; ++l) w9[l] = ldsw[s * 9 + l];
    const u16* __restrict__ y2b = Y2 + (size_t)b * E_DIM * S_DIM;
    float* __restrict__ ob = out + (size_t)b * E_DIM * S_DIM;
#pragma unroll
    for (int jj = 0; jj < 16; ++jj) {
      int f = fi * 16 + jj;
      const u16* __restrict__ row = y2b + (size_t)f * S_DIM;
      float o = 0.f;
#pragma unroll
      for (int l = 0; l < 9; ++l) {
        int t = s0 + s - 4 + l;
        float yv = (t >= 0 && t < S_DIM) ? bf2f(row[t]) : 0.f;
        o += w9[l] * yv;
      }
      ob[(size_t)f * S_DIM + s0 + s] = (o + bo[f]) * (1.0f / 9.0f);
    }
  }
}

// ---------------------------------------------------------------------------
extern "C" void kernel_launch(void* const* d_in, const int* in_sizes, int n_in,
                              void* d_out, int out_size, void* d_ws, size_t ws_size,
                              hipStream_t stream) {
  const float* x = (const float*)d_in[0];
  const float* Wq = (const float*)d_in[1];
  const float* bq = (const float*)d_in[2];
  const float* Wo = (const float*)d_in[3];
  const float* bo = (const float*)d_in[4];
  float* out = (float*)d_out;

  // ws: xT [0,8M) | Y1 [8M,16M) | Y2 [16M,24M) | weights bf16 [24M,...)
  u16* xT = (u16*)d_ws;
  u16* Y1 = (u16*)((char*)d_ws + ((size_t)8 << 20));
  u16* Y2 = (u16*)((char*)d_ws + ((size_t)16 << 20));
  u16* Wqb = (u16*)((char*)d_ws + ((size_t)24 << 20));
  u16* Wob = Wqb + 65536;

  transpose_convert<<<dim3(32, 4, 8), 256, 0, stream>>>(x, xT, Wq, Wo, Wqb, Wob);
  gemm_y<<<dim3(16, 4, 8), 256, 0, stream>>>(xT, Wqb, Wob, bq, Y1, Y2);
  band_blend<<<dim3(S_DIM / TS, B_DIM), 512, 0, stream>>>(Y1, Y2, bq, bo, out);
}

// Round 9
// 119.642 us; speedup vs baseline: 1.1545x; 1.1545x over previous
//
#include <hip/hip_runtime.h>

#define E_DIM 256
#define S_DIM 2048
#define B_DIM 8

typedef unsigned short u16;
typedef __bf16 bf16x8 __attribute__((ext_vector_type(8)));
typedef float f32x4 __attribute__((ext_vector_type(4)));
typedef u16 u16x8 __attribute__((ext_vector_type(8)));
typedef u16 u16x4 __attribute__((ext_vector_type(4)));

__device__ inline u16 f2bf(float f) {
  unsigned u = __builtin_bit_cast(unsigned, f);
  return (u16)((u + 0x7FFF + ((u >> 16) & 1)) >> 16);  // RTNE, finite inputs
}
__device__ inline float bf2f(u16 v) {
  unsigned u = ((unsigned)v) << 16;
  return __builtin_bit_cast(float, u);
}

// ---------------------------------------------------------------------------
// Prep: Wq, Wo (fp32 [f][e]) -> bf16 [f][e]
// ---------------------------------------------------------------------------
__global__ __launch_bounds__(256) void convert_w(
    const float* __restrict__ Wq, const float* __restrict__ Wo,
    u16* __restrict__ Wqb, u16* __restrict__ Wob) {
  int idx = (blockIdx.x * 256 + threadIdx.x) * 4;  // grid 128 -> 131072 elems
  const float* src;
  u16* dst;
  if (idx < 65536) { src = Wq + idx; dst = Wqb + idx; }
  else { src = Wo + (idx - 65536); dst = Wob + (idx - 65536); }
  float4 v = *(const float4*)src;
  *(ushort4*)dst = make_ushort4(f2bf(v.x), f2bf(v.y), f2bf(v.z), f2bf(v.w));
}

// ---------------------------------------------------------------------------
// K1: transpose-fused GEMM. Block = (b, 32-s tile), 512 thr, grid 512 = 2/CU.
// ONE barrier: stage xt[32][256] bf16 (in-register transpose of x), then
// 8 K-steps of MFMA with A from LDS, B (weights) from global (L2-resident).
// Waves 0-3: Y1[b][s][f] = q = xt.Wq^T + bq (bf16).
// Waves 4-7: Y2[b][f][s] = xt.Wo^T (bf16).
// ---------------------------------------------------------------------------
#define XSTR 264  // u16 row stride (132 dw: frag reads max 2-way = free)

__global__ __launch_bounds__(512) void gemm_qy(
    const float* __restrict__ x, const u16* __restrict__ Wqb,
    const u16* __restrict__ Wob, const float* __restrict__ bq,
    u16* __restrict__ Y1, u16* __restrict__ Y2) {
  __shared__ u16 xt[32 * XSTR];  // 16.5 KB
  const int tid = threadIdx.x;
  const int s0 = blockIdx.x * 32;
  const int b = blockIdx.y;
  const int wave = tid >> 6, lane = tid & 63;
  const int lm = lane & 15, lk = lane >> 4;

  // ---- stage xt: thread (s = tid&31, eg = tid>>5 covers 16 e) ----
  {
    const int s = tid & 31, eg = tid >> 5;
    const float* __restrict__ xb = x + ((size_t)b * E_DIM + eg * 16) * S_DIM + s0 + s;
    float v[16];
#pragma unroll
    for (int c = 0; c < 16; ++c) v[c] = xb[(size_t)c * S_DIM];  // coalesced over s
    u16x8 w0, w1;
#pragma unroll
    for (int u = 0; u < 8; ++u) { w0[u] = f2bf(v[u]); w1[u] = f2bf(v[8 + u]); }
    *(u16x8*)&xt[s * XSTR + eg * 16] = w0;
    *(u16x8*)&xt[s * XSTR + eg * 16 + 8] = w1;
  }
  __syncthreads();

  // ---- K-loop: wave half 0 -> Wq, half 1 -> Wo; 64-f slice per wave ----
  const int half = wave >> 2;
  const int wf = (wave & 3) * 64;
  const u16* __restrict__ W = half ? Wob : Wqb;

  const f32x4 zero = {0.f, 0.f, 0.f, 0.f};
  f32x4 acc[2][4];
#pragma unroll
  for (int i = 0; i < 2; ++i)
#pragma unroll
    for (int j = 0; j < 4; ++j) acc[i][j] = zero;

#pragma unroll
  for (int k0 = 0; k0 < 8; ++k0) {
    bf16x8 af[2], bfr[4];
#pragma unroll
    for (int i = 0; i < 2; ++i)
      af[i] = *(const bf16x8*)&xt[(i * 16 + lm) * XSTR + k0 * 32 + lk * 8];
#pragma unroll
    for (int j = 0; j < 4; ++j)
      bfr[j] = *(const bf16x8*)&W[(size_t)(wf + j * 16 + lm) * E_DIM + k0 * 32 + lk * 8];
#pragma unroll
    for (int i = 0; i < 2; ++i)
#pragma unroll
      for (int j = 0; j < 4; ++j)
        acc[i][j] = __builtin_amdgcn_mfma_f32_16x16x32_bf16(af[i], bfr[j], acc[i][j], 0, 0, 0);
  }

  if (half == 0) {
    // Y1[b][s][f] = acc + bq[f]
#pragma unroll
    for (int j = 0; j < 4; ++j) {
      int f = wf + j * 16 + lm;
      float bv = bq[f];
#pragma unroll
      for (int i = 0; i < 2; ++i) {
        int m = i * 16 + lk * 4;
        size_t base = ((size_t)b * S_DIM + s0 + m) * E_DIM + f;
#pragma unroll
        for (int r = 0; r < 4; ++r)
          Y1[base + (size_t)r * E_DIM] = f2bf(acc[i][j][r] + bv);
      }
    }
  } else {
    // Y2[b][f][s]
#pragma unroll
    for (int j = 0; j < 4; ++j) {
      int f = wf + j * 16 + lm;
#pragma unroll
      for (int i = 0; i < 2; ++i) {
        int s = s0 + i * 16 + lk * 4;
        ushort4 v = make_ushort4(f2bf(acc[i][j][0]), f2bf(acc[i][j][1]),
                                 f2bf(acc[i][j][2]), f2bf(acc[i][j][3]));
        *(ushort4*)&Y2[((size_t)b * E_DIM + f) * S_DIM + s] = v;
      }
    }
  }
}

// ---------------------------------------------------------------------------
// K2: band kernel. Block = (b, 32-s tile), 512 thr, one barrier.
//  S: stage Y2 tile [256 f][48 s] bf16 covering t = s0-8 .. s0+39 (8-aligned
//     chunks: every chunk fully in-bounds or fully zero) - 3 u16x8 loads/thr,
//     issued BEFORE phase E so latency hides under energy compute.
//  E: energy[s][l] = Y1[s].Y1[s+l-4]/24 (OOB row -> bq), in-wave reduce,
//     softmax -> ldsw[32][9]
//  B: out[b][f][s] = (sum_l w[s][l]*y2t[f][s+4+l] + bo[f]) / 9   (from LDS)
// ---------------------------------------------------------------------------
#define TS 32
#define YSTR 48

__global__ __launch_bounds__(512) void band_out(
    const u16* __restrict__ Y1, const u16* __restrict__ Y2,
    const float* __restrict__ bq, const float* __restrict__ bo,
    float* __restrict__ out) {
  __shared__ u16 y2t[256 * YSTR];  // 24 KB
  __shared__ float ldsw[TS * 9];
  const int tid = threadIdx.x;
  const int s0 = blockIdx.x * TS;
  const int b = blockIdx.y;
  const int wave = tid >> 6, lane = tid & 63;

  // ---- S: stage Y2 tile (issue first; hides under phase E) ----
  {
    const u16* __restrict__ y2b = Y2 + (size_t)b * E_DIM * S_DIM;
#pragma unroll
    for (int c = tid; c < 256 * 6; c += 512) {
      int f = c / 6, k = c - f * 6;
      int t0 = s0 - 8 + 8 * k;  // 8-aligned: fully in or fully out
      u16x8 v = {0, 0, 0, 0, 0, 0, 0, 0};
      if (t0 >= 0 && t0 < S_DIM) v = *(const u16x8*)&y2b[(size_t)f * S_DIM + t0];
      *(u16x8*)&y2t[f * YSTR + 8 * k] = v;
    }
  }

  // ---- E: wave owns s-rows 4w..4w+3; lane halves take si pairs ----
  {
    const int half = lane >> 5;
    const int fl = lane & 31;
    const int sbase = half * 2;
    const u16* __restrict__ y1b = Y1 + (size_t)b * S_DIM * E_DIM;
    float accE[2][9];
#pragma unroll
    for (int si = 0; si < 2; ++si)
#pragma unroll
      for (int l = 0; l < 9; ++l) accE[si][l] = 0.f;
#pragma unroll
    for (int fc = 0; fc < 2; ++fc) {
      int fbase = fl * 8 + fc * 4;
      float4 rr[10];
#pragma unroll
      for (int i = 0; i < 10; ++i) {
        int t = s0 + 4 * wave + sbase - 4 + i;  // wave-uniform branch
        if (t >= 0 && t < S_DIM) {
          u16x4 v = *(const u16x4*)&y1b[(size_t)t * E_DIM + fbase];
          rr[i] = make_float4(bf2f(v[0]), bf2f(v[1]), bf2f(v[2]), bf2f(v[3]));
        } else {
          rr[i] = *(const float4*)&bq[fbase];
        }
      }
#pragma unroll
      for (int si = 0; si < 2; ++si) {
        float4 c = rr[si + 4];
#pragma unroll
        for (int l = 0; l < 9; ++l) {
          float4 r = rr[si + l];
          accE[si][l] += c.x * r.x + c.y * r.y + c.z * r.z + c.w * r.w;
        }
      }
    }
#pragma unroll
    for (int off = 1; off < 32; off <<= 1)
#pragma unroll
      for (int si = 0; si < 2; ++si)
#pragma unroll
        for (int l = 0; l < 9; ++l) accE[si][l] += __shfl_xor(accE[si][l], off, 64);
    if (fl == 0) {
#pragma unroll
      for (int si = 0; si < 2; ++si) {
        int s = 4 * wave + sbase + si;
        float e[9];
#pragma unroll
        for (int l = 0; l < 9; ++l) e[l] = accE[si][l] * (1.0f / 24.0f);
        float m = e[0];
#pragma unroll
        for (int l = 1; l < 9; ++l) m = fmaxf(m, e[l]);
        float sum = 0.f;
#pragma unroll
        for (int l = 0; l < 9; ++l) { e[l] = __expf(e[l] - m); sum += e[l]; }
        float inv = 1.0f / sum;
#pragma unroll
        for (int l = 0; l < 9; ++l) ldsw[s * 9 + l] = e[l] * inv;
      }
    }
  }
  __syncthreads();

  // ---- B: blend from LDS tile ----
  {
    const int s = tid & 31;   // lane-contiguous s: coalesced stores
    const int fi = tid >> 5;  // 0..15
    float w9[9];
#pragma unroll
    for (int l = 0; l < 9; ++l) w9[l] = ldsw[s * 9 + l];
    float* __restrict__ ob = out + (size_t)b * E_DIM * S_DIM + s0 + s;
#pragma unroll
    for (int jj = 0; jj < 16; ++jj) {
      int f = fi * 16 + jj;
      const u16* __restrict__ row = &y2t[f * YSTR + s + 4];
      float o = 0.f;
#pragma unroll
      for (int l = 0; l < 9; ++l) o += w9[l] * bf2f(row[l]);
      ob[(size_t)f * S_DIM] = (o + bo[f]) * (1.0f / 9.0f);
    }
  }
}

// ---------------------------------------------------------------------------
extern "C" void kernel_launch(void* const* d_in, const int* in_sizes, int n_in,
                              void* d_out, int out_size, void* d_ws, size_t ws_size,
                              hipStream_t stream) {
  const float* x = (const float*)d_in[0];
  const float* Wq = (const float*)d_in[1];
  const float* bq = (const float*)d_in[2];
  const float* Wo = (const float*)d_in[3];
  const float* bo = (const float*)d_in[4];
  float* out = (float*)d_out;

  // ws: Y1 [0,8M) | Y2 [8M,16M) | weights bf16 [16M,...)
  u16* Y1 = (u16*)d_ws;
  u16* Y2 = (u16*)((char*)d_ws + ((size_t)8 << 20));
  u16* Wqb = (u16*)((char*)d_ws + ((size_t)16 << 20));
  u16* Wob = Wqb + 65536;

  convert_w<<<128, 256, 0, stream>>>(Wq, Wo, Wqb, Wob);
  gemm_qy<<<dim3(S_DIM / 32, B_DIM), 512, 0, stream>>>(x, Wqb, Wob, bq, Y1, Y2);
  band_out<<<dim3(S_DIM / TS, B_DIM), 512, 0, stream>>>(Y1, Y2, bq, bo, out);
}

// Round 10
// 99.033 us; speedup vs baseline: 1.3947x; 1.2081x over previous
//
#include <hip/hip_runtime.h>

#define E_DIM 256
#define S_DIM 2048
#define B_DIM 8

typedef unsigned short u16;
typedef __bf16 bf16x8 __attribute__((ext_vector_type(8)));
typedef float f32x4 __attribute__((ext_vector_type(4)));
typedef u16 u16x8 __attribute__((ext_vector_type(8)));

__device__ inline u16 f2bf(float f) {
  unsigned u = __builtin_bit_cast(unsigned, f);
  return (u16)((u + 0x7FFF + ((u >> 16) & 1)) >> 16);  // RTNE, finite inputs
}
__device__ inline float bf2f(u16 v) {
  unsigned u = ((unsigned)v) << 16;
  return __builtin_bit_cast(float, u);
}

// ---------------------------------------------------------------------------
// Prep: Wq, Wo (fp32 [f][e]) -> bf16 [f][e]
// ---------------------------------------------------------------------------
__global__ __launch_bounds__(256) void convert_w(
    const float* __restrict__ Wq, const float* __restrict__ Wo,
    u16* __restrict__ Wqb, u16* __restrict__ Wob) {
  int idx = (blockIdx.x * 256 + threadIdx.x) * 4;  // grid 128 -> 131072 elems
  const float* src;
  u16* dst;
  if (idx < 65536) { src = Wq + idx; dst = Wqb + idx; }
  else { src = Wo + (idx - 65536); dst = Wob + (idx - 65536); }
  float4 v = *(const float4*)src;
  *(ushort4*)dst = make_ushort4(f2bf(v.x), f2bf(v.y), f2bf(v.z), f2bf(v.w));
}

// ---------------------------------------------------------------------------
// Fused: one block = (b, 32-s tile), 512 threads (8 waves), grid 512 = 2/CU.
// 4 barriers.
//  P0: stage xt[r][e] bf16, r=0..47 (t = s0-4+r; r>=40 or OOB -> 0)
//  P1: q = xt.Wq^T + bq (MFMA, M=48 N=256 K=256) -> qt bf16 rows 0..39
//  PE: energies via MFMA (waves 0,1): E[s][l] = qt[s+4].qt[s+l] / 24.
//      Wave w: m-frag = qt rows 4+16w+lm; n-frags at rows {16w, 16w+16|24}.
//      Banded C elements scattered to eb[32][9]; softmax IN-WAVE (no extra
//      barrier: each wave's s-band lives entirely in that wave), in-place.
//  P3: pooled[s][e] = sum_l w[s][l]*xt[s+l][e] (bf16, aliases qt)
//  P4: out[b][f][s] = (pooled.Wo^T + bo)/9 (MFMA, M=32 N=256 K=256)
// Zero-staged OOB rows give q_row = bq and zero-padded pooling exactly.
// ---------------------------------------------------------------------------
#define TS 32
#define QR 40      // valid q rows: t = s0-4 .. s0+35
#define XROWS 48   // padded to 3 m-frags
#define XSTR 264   // u16 row stride (132 dw: b128 frag reads conflict-free)
#define QSTR 264
#define PSTR 264

__global__ __launch_bounds__(512) void fused_attn(
    const float* __restrict__ x, const u16* __restrict__ Wqb,
    const float* __restrict__ bq, const u16* __restrict__ Wob,
    const float* __restrict__ bo, float* __restrict__ out) {
  // LDS: xt 25344 | qt 21120 (pooled 16896 aliases) | eb 1152 = 47616 B
  __shared__ __align__(16) char smem[47616];
  u16* xt = (u16*)smem;
  u16* qt = (u16*)(smem + 25344);
  u16* pooled = qt;
  float* eb = (float*)(smem + 46464);  // [32][9] energies -> softmax weights

  const int tid = threadIdx.x;
  const int s0 = blockIdx.x * TS;
  const int b = blockIdx.y;
  const int wave = tid >> 6, lane = tid & 63;
  const int lm = lane & 15, lk = lane >> 4;

  // ---- P0: stage xt. lane = row (valid < 48), wave = 32-e slice ----
  {
    const int r = lane;
    const int t = s0 - 4 + r;
    const bool v = (r < QR) && (t >= 0) && (t < S_DIM);
    if (r < XROWS) {
      const float* __restrict__ xb = x + (size_t)b * E_DIM * S_DIM + t;
      const int ebase = wave * 32;
#pragma unroll
      for (int c = 0; c < 4; ++c) {
        u16x8 v8;
#pragma unroll
        for (int u = 0; u < 8; ++u) {
          float xv = v ? xb[(size_t)(ebase + c * 8 + u) * S_DIM] : 0.f;
          v8[u] = f2bf(xv);
        }
        *(u16x8*)&xt[r * XSTR + ebase + c * 8] = v8;
      }
    }
  }
  __syncthreads();

  // ---- P1: K1 MFMA -> qt rows 0..39 (M=48, wave f-slice wave*32) ----
  {
    const f32x4 zero = {0.f, 0.f, 0.f, 0.f};
    f32x4 acc[3][2];
#pragma unroll
    for (int i = 0; i < 3; ++i)
#pragma unroll
      for (int j = 0; j < 2; ++j) acc[i][j] = zero;
#pragma unroll
    for (int k0 = 0; k0 < 8; ++k0) {
      bf16x8 af[3], bfr[2];
#pragma unroll
      for (int i = 0; i < 3; ++i)
        af[i] = *(const bf16x8*)&xt[(i * 16 + lm) * XSTR + k0 * 32 + lk * 8];
#pragma unroll
      for (int j = 0; j < 2; ++j)
        bfr[j] = *(const bf16x8*)&Wqb[(size_t)(wave * 32 + j * 16 + lm) * E_DIM +
                                      k0 * 32 + lk * 8];
#pragma unroll
      for (int i = 0; i < 3; ++i)
#pragma unroll
        for (int j = 0; j < 2; ++j)
          acc[i][j] = __builtin_amdgcn_mfma_f32_16x16x32_bf16(af[i], bfr[j], acc[i][j], 0, 0, 0);
    }
#pragma unroll
    for (int j = 0; j < 2; ++j) {
      int f = wave * 32 + j * 16 + lm;
      float bv = bq[f];
#pragma unroll
      for (int i = 0; i < 3; ++i) {
        int row = i * 16 + lk * 4;
#pragma unroll
        for (int r2 = 0; r2 < 4; ++r2)
          if (row + r2 < QR) qt[(row + r2) * QSTR + f] = f2bf(acc[i][j][r2] + bv);
      }
    }
  }
  __syncthreads();

  // ---- PE: banded energies via MFMA + in-wave softmax (waves 0,1) ----
  if (wave < 2) {
    const int nb0 = wave * 16;          // n-frag 0: qt rows nb0..nb0+15
    const int nb1 = wave ? 24 : 16;     // n-frag 1
    const f32x4 zero = {0.f, 0.f, 0.f, 0.f};
    f32x4 accA = zero, accB = zero;
#pragma unroll
    for (int k0 = 0; k0 < 8; ++k0) {
      bf16x8 af = *(const bf16x8*)&qt[(4 + nb0 + lm) * QSTR + k0 * 32 + lk * 8];
      bf16x8 b0 = *(const bf16x8*)&qt[(nb0 + lm) * QSTR + k0 * 32 + lk * 8];
      bf16x8 b1 = *(const bf16x8*)&qt[(nb1 + lm) * QSTR + k0 * 32 + lk * 8];
      accA = __builtin_amdgcn_mfma_f32_16x16x32_bf16(af, b0, accA, 0, 0, 0);
      accB = __builtin_amdgcn_mfma_f32_16x16x32_bf16(af, b1, accB, 0, 0, 0);
    }
    // scatter banded C elements: C row = s (local to m-tile), col = n
#pragma unroll
    for (int r = 0; r < 4; ++r) {
      int s = nb0 + lk * 4 + r;         // output s in 0..31
      int l0 = (nb0 + lm) - s;          // qt-row minus s
      if (l0 >= 0 && l0 <= 8) eb[s * 9 + l0] = accA[r];
      int sp1 = nb1 + lm;
      int l1 = sp1 - s;
      if (l1 >= 0 && l1 <= 8 && sp1 >= nb0 + 16) eb[s * 9 + l1] = accB[r];
    }
    // in-wave softmax over l (this wave's s-band is entirely wave-local)
    if (lane < 16) {
      int s = nb0 + lane;
      float e[9];
#pragma unroll
      for (int l = 0; l < 9; ++l) e[l] = eb[s * 9 + l] * (1.0f / 24.0f);
      float m = e[0];
#pragma unroll
      for (int l = 1; l < 9; ++l) m = fmaxf(m, e[l]);
      float sum = 0.f;
#pragma unroll
      for (int l = 0; l < 9; ++l) { e[l] = __expf(e[l] - m); sum += e[l]; }
      float inv = 1.0f / sum;
#pragma unroll
      for (int l = 0; l < 9; ++l) eb[s * 9 + l] = e[l] * inv;
    }
  }
  __syncthreads();

  // ---- P3: pooled[s][e] = sum_l w[s][l] * xt[s+l][e]  (overlays qt) ----
  {
    const int s = tid & 31, ep = tid >> 5;  // ep 0..15, 16 e each
    float w9[9];
#pragma unroll
    for (int l = 0; l < 9; ++l) w9[l] = eb[s * 9 + l];
#pragma unroll
    for (int c = 0; c < 2; ++c) {
      int e8 = ep * 16 + c * 8;
      float o[8];
#pragma unroll
      for (int u = 0; u < 8; ++u) o[u] = 0.f;
#pragma unroll
      for (int l = 0; l < 9; ++l) {
        u16x8 xv = *(const u16x8*)&xt[(s + l) * XSTR + e8];
#pragma unroll
        for (int u = 0; u < 8; ++u) o[u] += w9[l] * bf2f(xv[u]);
      }
      u16x8 pv;
#pragma unroll
      for (int u = 0; u < 8; ++u) pv[u] = f2bf(o[u]);
      *(u16x8*)&pooled[s * PSTR + e8] = pv;
    }
  }
  __syncthreads();

  // ---- P4: K3 MFMA -> out[b][f][s] (M=32, wave f-slice wave*32) ----
  {
    const f32x4 zero = {0.f, 0.f, 0.f, 0.f};
    f32x4 acc[2][2];
#pragma unroll
    for (int i = 0; i < 2; ++i)
#pragma unroll
      for (int j = 0; j < 2; ++j) acc[i][j] = zero;
#pragma unroll
    for (int k0 = 0; k0 < 8; ++k0) {
      bf16x8 af[2], bfr[2];
#pragma unroll
      for (int i = 0; i < 2; ++i)
        af[i] = *(const bf16x8*)&pooled[(i * 16 + lm) * PSTR + k0 * 32 + lk * 8];
#pragma unroll
      for (int j = 0; j < 2; ++j)
        bfr[j] = *(const bf16x8*)&Wob[(size_t)(wave * 32 + j * 16 + lm) * E_DIM +
                                      k0 * 32 + lk * 8];
#pragma unroll
      for (int i = 0; i < 2; ++i)
#pragma unroll
        for (int j = 0; j < 2; ++j)
          acc[i][j] = __builtin_amdgcn_mfma_f32_16x16x32_bf16(af[i], bfr[j], acc[i][j], 0, 0, 0);
    }
#pragma unroll
    for (int j = 0; j < 2; ++j) {
      int f = wave * 32 + j * 16 + lm;
      float bv = bo[f];
#pragma unroll
      for (int i = 0; i < 2; ++i) {
        int s = s0 + i * 16 + lk * 4;
        float4 w = make_float4((acc[i][j][0] + bv) * (1.0f / 9.0f),
                               (acc[i][j][1] + bv) * (1.0f / 9.0f),
                               (acc[i][j][2] + bv) * (1.0f / 9.0f),
                               (acc[i][j][3] + bv) * (1.0f / 9.0f));
        *(float4*)&out[((size_t)b * E_DIM + f) * S_DIM + s] = w;
      }
    }
  }
}

// ---------------------------------------------------------------------------
extern "C" void kernel_launch(void* const* d_in, const int* in_sizes, int n_in,
                              void* d_out, int out_size, void* d_ws, size_t ws_size,
                              hipStream_t stream) {
  const float* x = (const float*)d_in[0];
  const float* Wq = (const float*)d_in[1];
  const float* bq = (const float*)d_in[2];
  const float* Wo = (const float*)d_in[3];
  const float* bo = (const float*)d_in[4];
  float* out = (float*)d_out;

  u16* Wqb = (u16*)d_ws;
  u16* Wob = Wqb + 65536;

  convert_w<<<128, 256, 0, stream>>>(Wq, Wo, Wqb, Wob);
  fused_attn<<<dim3(S_DIM / TS, B_DIM), 512, 0, stream>>>(x, Wqb, bq, Wob, bo, out);
}